// Round 1
// baseline (753.053 us; speedup 1.0000x reference)
//
#include <hip/hip_runtime.h>
#include <math.h>

#define NB 4
#define NPT 4096
#define KNN 20
#define C1 64
#define C2 128
#define C3 256
#define BN_EPS 1e-5f

// ---------------- K0: pack {x,y,z,xx} ----------------
__global__ __launch_bounds__(256) void k0_pack(const float* __restrict__ x, float4* __restrict__ xp) {
  int i = blockIdx.x * 256 + threadIdx.x;
  if (i >= NB * NPT) return;
  float a = x[i*3+0], b = x[i*3+1], c = x[i*3+2];
  float xx = fmaf(c, c, fmaf(b, b, a*a));
  xp[i] = make_float4(a, b, c, xx);
}

// ---------------- K1: exact top-K (f64-packed keys) ----------------
__global__ __launch_bounds__(64) void k1_knn(const float4* __restrict__ xp, int* __restrict__ nbr) {
  __shared__ float4 pts[NPT];                       // 64 KiB
  int b = blockIdx.x >> 6;                          // 64 blocks per batch
  int n = ((blockIdx.x & 63) << 6) | threadIdx.x;
  const float4* xb = xp + b * NPT;
  for (int t = threadIdx.x; t < NPT; t += 64) pts[t] = xb[t];
  __syncthreads();

  float4 q = pts[n];
  float nxx = -q.w;
  double keys[KNN];
#pragma unroll
  for (int t = 0; t < KNN; ++t) keys[t] = -INFINITY;

  for (int j = 0; j < NPT; ++j) {
    float4 c = pts[j];                              // wave-uniform -> LDS broadcast
    float dot = fmaf(q.z, c.z, fmaf(q.y, c.y, q.x * c.x));
    float inner = -2.0f * dot;
    float pd = (nxx - inner) - c.w;                 // matches ref formula
    // pack: f32->f64 leaves 29 zero mantissa bits; OR 12-bit index.
    // negative pd: smaller j -> smaller mantissa -> LESS negative -> wins max (stable tie-break)
    double key = __longlong_as_double(__double_as_longlong((double)pd) | (long long)j);
    if (key > keys[KNN-1]) {
      double cv = key;
#pragma unroll
      for (int t = 0; t < KNN; ++t) {
        double hi = fmax(cv, keys[t]);
        cv = fmin(cv, keys[t]);
        keys[t] = hi;
      }
    }
  }
  int* out = nbr + (size_t)(b * NPT + n) * KNN;
#pragma unroll
  for (int t = 0; t < KNN; ++t) out[t] = (int)(__double_as_longlong(keys[t]) & 0xFFF);
}

// ---------------- K2: edge-conv 6->64 + BN + ReLU + max over K ----------------
__global__ __launch_bounds__(64) void k2_edge(const float4* __restrict__ xp, const int* __restrict__ nbr,
    const float* __restrict__ w1, const float* __restrict__ g1, const float* __restrict__ b1,
    const float* __restrict__ m1, const float* __restrict__ v1, float* __restrict__ h1) {
  __shared__ float4 sa[C1], se[C1];
  int b = blockIdx.x >> 6;
  int n = ((blockIdx.x & 63) << 6) | threadIdx.x;
  {
    int o = threadIdx.x;                            // 64 threads == C1
    float inv = g1[o] / sqrtf(v1[o] + BN_EPS);
    float bb = b1[o] - m1[o] * inv;
    const float* w = w1 + o * 6;
    sa[o] = make_float4(w[0]*inv, w[1]*inv, w[2]*inv, 0.f);
    se[o] = make_float4((w[3]-w[0])*inv, (w[4]-w[1])*inv, (w[5]-w[2])*inv, bb);
  }
  __syncthreads();
  const float4* xb = xp + b * NPT;
  float4 q = xb[n];
  float4 nb[KNN];
  const int* nr = nbr + (size_t)(b * NPT + n) * KNN;
#pragma unroll
  for (int k = 0; k < KNN; ++k) nb[k] = xb[nr[k]];
  float* out = h1 + (size_t)(b * NPT + n) * C1;
#pragma unroll 1
  for (int o = 0; o < C1; o += 4) {
    float4 res;
    float* rp = &res.x;
#pragma unroll
    for (int oo = 0; oo < 4; ++oo) {
      float4 a = sa[o+oo], e = se[o+oo];
      float mx = -INFINITY;
#pragma unroll
      for (int k = 0; k < KNN; ++k)
        mx = fmaxf(mx, fmaf(a.z, nb[k].z, fmaf(a.y, nb[k].y, a.x * nb[k].x)));
      float base = fmaf(e.z, q.z, fmaf(e.y, q.y, e.x * q.x)) + e.w;
      rp[oo] = fmaxf(mx + base, 0.f);
    }
    *(float4*)(out + o) = res;
  }
}

// ---------------- K3: conv 64->128 + BN + ReLU ----------------
__global__ __launch_bounds__(64) void k3_conv2(const float* __restrict__ h1,
    const float* __restrict__ w2, const float* __restrict__ g2, const float* __restrict__ b2,
    const float* __restrict__ m2, const float* __restrict__ v2, float* __restrict__ h2) {
  __shared__ float4 sw[C2 * 16];                    // 32 KiB folded weights
  __shared__ float sb[C2], sinv[C2];
  int b = blockIdx.x >> 6;
  int n = ((blockIdx.x & 63) << 6) | threadIdx.x;
  for (int o = threadIdx.x; o < C2; o += 64) {
    float inv = g2[o] / sqrtf(v2[o] + BN_EPS);
    sinv[o] = inv;
    sb[o] = b2[o] - m2[o] * inv;
  }
  __syncthreads();
  for (int t = threadIdx.x; t < C2 * 16; t += 64) {
    float4 w = ((const float4*)w2)[t];
    float inv = sinv[t >> 4];
    sw[t] = make_float4(w.x*inv, w.y*inv, w.z*inv, w.w*inv);
  }
  __syncthreads();
  float4 r[16];
  const float4* row = (const float4*)(h1 + (size_t)(b * NPT + n) * C1);
#pragma unroll
  for (int i = 0; i < 16; ++i) r[i] = row[i];
  float* out = h2 + (size_t)(b * NPT + n) * C2;
#pragma unroll 1
  for (int o = 0; o < C2; o += 4) {
    float4 res;
    float* rp = &res.x;
#pragma unroll
    for (int oo = 0; oo < 4; ++oo) {
      const float4* wrow = &sw[(o+oo) * 16];
      float acc = 0.f;
#pragma unroll
      for (int i = 0; i < 16; ++i) {
        float4 w = wrow[i];
        acc = fmaf(r[i].x, w.x, acc);
        acc = fmaf(r[i].y, w.y, acc);
        acc = fmaf(r[i].z, w.z, acc);
        acc = fmaf(r[i].w, w.w, acc);
      }
      rp[oo] = fmaxf(acc + sb[o+oo], 0.f);
    }
    *(float4*)(out + o) = res;
  }
}

// ---------------- K4: conv 128->256 + BN + ReLU fused with global max over N ----------------
__global__ __launch_bounds__(256) void k4_conv3max(const float* __restrict__ h2,
    const float* __restrict__ w3, const float* __restrict__ g3, const float* __restrict__ b3,
    const float* __restrict__ m3, const float* __restrict__ v3, float* __restrict__ feat) {
  __shared__ float4 sw[64 * 32];                    // 32 KiB (quarter of w3, folded)
  __shared__ float sb[64], sinv[64];
  __shared__ float lw[4 * 64];
  int bid = blockIdx.x;
  int oq = bid & 3, nt = (bid >> 2) & 15, b = bid >> 6;
  int obase = oq * 64;
  if (threadIdx.x < 64) {
    int o = obase + threadIdx.x;
    float inv = g3[o] / sqrtf(v3[o] + BN_EPS);
    sinv[threadIdx.x] = inv;
    sb[threadIdx.x] = b3[o] - m3[o] * inv;
  }
  __syncthreads();
  for (int t = threadIdx.x; t < 64 * 32; t += 256) {
    float4 w = ((const float4*)w3)[obase * 32 + t];
    float inv = sinv[t >> 5];
    sw[t] = make_float4(w.x*inv, w.y*inv, w.z*inv, w.w*inv);
  }
  __syncthreads();
  int n = nt * 256 + threadIdx.x;
  float4 r[32];
  const float4* row = (const float4*)(h2 + (size_t)(b * NPT + n) * C2);
#pragma unroll
  for (int i = 0; i < 32; ++i) r[i] = row[i];
  int lane = threadIdx.x & 63, wid = threadIdx.x >> 6;
#pragma unroll 1
  for (int ol = 0; ol < 64; ++ol) {
    const float4* wrow = &sw[ol * 32];
    float acc = 0.f;
#pragma unroll
    for (int i = 0; i < 32; ++i) {
      float4 w = wrow[i];
      acc = fmaf(r[i].x, w.x, acc);
      acc = fmaf(r[i].y, w.y, acc);
      acc = fmaf(r[i].z, w.z, acc);
      acc = fmaf(r[i].w, w.w, acc);
    }
    float v = fmaxf(acc + sb[ol], 0.f);
#pragma unroll
    for (int m = 32; m; m >>= 1) v = fmaxf(v, __shfl_xor(v, m));
    if (lane == 0) lw[wid * 64 + ol] = v;
  }
  __syncthreads();
  if (threadIdx.x < 64) {
    float m0 = fmaxf(fmaxf(lw[threadIdx.x], lw[64 + threadIdx.x]),
                     fmaxf(lw[128 + threadIdx.x], lw[192 + threadIdx.x]));
    // relu output >= 0 -> int-bits compare == float compare
    atomicMax((int*)feat + b * C3 + obase + threadIdx.x, __float_as_int(m0));
  }
}

// ---------------- K6: FC head ----------------
__global__ __launch_bounds__(256) void k6_fc(const float* __restrict__ feat,
    const float* __restrict__ fc1w, const float* __restrict__ fc1b,
    const float* __restrict__ fc2w, const float* __restrict__ fc2b, float* __restrict__ out) {
  __shared__ float sf[NB * C3];
  __shared__ float sh[NB * 128];
  for (int t = threadIdx.x; t < NB * C3; t += 256) sf[t] = feat[t];
  __syncthreads();
  for (int t = threadIdx.x; t < NB * 128; t += 256) {
    int b = t >> 7, o = t & 127;
    float acc = fc1b[o];
    const float* w = fc1w + o * C3;
    const float* f = sf + b * C3;
    for (int c = 0; c < C3; ++c) acc = fmaf(f[c], w[c], acc);
    sh[t] = fmaxf(acc, 0.f);
  }
  __syncthreads();
  for (int t = threadIdx.x; t < NB * 40; t += 256) {
    int b = t / 40, o = t % 40;
    float acc = fc2b[o];
    const float* w = fc2w + o * 128;
    const float* hh = sh + b * 128;
    for (int c = 0; c < 128; ++c) acc = fmaf(hh[c], w[c], acc);
    out[b * 40 + o] = acc;
  }
}

extern "C" void kernel_launch(void* const* d_in, const int* in_sizes, int n_in,
                              void* d_out, int out_size, void* d_ws, size_t ws_size,
                              hipStream_t stream) {
  (void)in_sizes; (void)n_in; (void)out_size; (void)ws_size;
  const float* x   = (const float*)d_in[0];
  const float* w1  = (const float*)d_in[1];
  const float* g1  = (const float*)d_in[2];
  const float* b1  = (const float*)d_in[3];
  const float* m1  = (const float*)d_in[4];
  const float* v1  = (const float*)d_in[5];
  const float* w2  = (const float*)d_in[6];
  const float* g2  = (const float*)d_in[7];
  const float* b2  = (const float*)d_in[8];
  const float* m2  = (const float*)d_in[9];
  const float* v2  = (const float*)d_in[10];
  const float* w3  = (const float*)d_in[11];
  const float* g3  = (const float*)d_in[12];
  const float* b3  = (const float*)d_in[13];
  const float* m3  = (const float*)d_in[14];
  const float* v3  = (const float*)d_in[15];
  const float* f1w = (const float*)d_in[16];
  const float* f1b = (const float*)d_in[17];
  const float* f2w = (const float*)d_in[18];
  const float* f2b = (const float*)d_in[19];

  char* ws = (char*)d_ws;
  float4* xp  = (float4*)ws;                        // 256 KiB
  int*    nbr = (int*)(ws + (1 << 20));             // 1.25 MiB
  float*  h1  = (float*)(ws + (3u << 20));          // 4 MiB
  float*  h2  = (float*)(ws + (7u << 20));          // 8 MiB
  float*  feat= (float*)(ws + (15u << 20));         // 4 KiB

  hipMemsetAsync(feat, 0, NB * C3 * sizeof(float), stream);
  k0_pack   <<<64, 256, 0, stream>>>(x, xp);
  k1_knn    <<<256, 64, 0, stream>>>(xp, nbr);
  k2_edge   <<<256, 64, 0, stream>>>(xp, nbr, w1, g1, b1, m1, v1, h1);
  k3_conv2  <<<256, 64, 0, stream>>>(h1, w2, g2, b2, m2, v2, h2);
  k4_conv3max<<<256, 256, 0, stream>>>(h2, w3, g3, b3, m3, v3, feat);
  k6_fc     <<<1, 256, 0, stream>>>(feat, f1w, f1b, f2w, f2b, (float*)d_out);
}

// Round 2
// 316.261 us; speedup vs baseline: 2.3811x; 2.3811x over previous
//
#include <hip/hip_runtime.h>
#include <math.h>

#define NB 4
#define NPT 4096
#define KNN 20
#define C1 64
#define C2 128
#define C3 256
#define BN_EPS 1e-5f
#define NCH 16
#define CHSZ 256   // NPT / NCH

// pd must be computed bit-identically in k1_part and k1_merge: pin contraction off.
__device__ __forceinline__ float pd_of(float4 q, float nxx, float4 c) {
#pragma clang fp contract(off)
  float dot = fmaf(q.z, c.z, fmaf(q.y, c.y, q.x * c.x));
  float inner = -2.0f * dot;
  return (nxx - inner) - c.w;
}

// key: f64(pd) with 12-bit candidate index OR'd into the zero low mantissa bits.
// Unique per candidate; for negative pd larger index -> more negative -> max prefers
// smaller index (matches lax.top_k tie-break). Verified exact in round 1.
__device__ __forceinline__ double pack_key(float pd, int j) {
  return __longlong_as_double(__double_as_longlong((double)pd) | (long long)j);
}

// ---------------- K0: pack {x,y,z,xx} ----------------
__global__ __launch_bounds__(256) void k0_pack(const float* __restrict__ x, float4* __restrict__ xp) {
  int i = blockIdx.x * 256 + threadIdx.x;
  if (i >= NB * NPT) return;
  float a = x[i*3+0], b = x[i*3+1], c = x[i*3+2];
  float xx = fmaf(c, c, fmaf(b, b, a*a));
  xp[i] = make_float4(a, b, c, xx);
}

// ---------------- K1a: per-chunk partial top-20 (indices only) ----------------
__global__ __launch_bounds__(256) void k1_part(const float4* __restrict__ xp,
                                               unsigned short* __restrict__ part) {
  __shared__ float4 pts[CHSZ];
  int blk = blockIdx.x;                 // 1024 blocks = 64 qgroups x 16 chunks
  int ch = blk & (NCH - 1);
  int qg = blk >> 4;                    // 0..63
  int b = qg >> 4;                      // 16 qgroups per batch
  int qbase = (qg & 15) << 8;
  const float4* xb = xp + b * NPT;
  int cbase = ch * CHSZ;
  pts[threadIdx.x] = xb[cbase + threadIdx.x];
  __syncthreads();

  int n = qbase + threadIdx.x;
  float4 q = xb[n];
  float nxx = -q.w;
  double keys[KNN];
#pragma unroll
  for (int t = 0; t < KNN; ++t) keys[t] = -INFINITY;

  for (int j = 0; j < CHSZ; ++j) {
    float4 c = pts[j];                  // wave-uniform LDS broadcast
    float pd = pd_of(q, nxx, c);
    double key = pack_key(pd, cbase + j);
    if (key > keys[KNN-1]) {
      double cv = key;
#pragma unroll
      for (int t = 0; t < KNN; ++t) {
        double hi = fmax(cv, keys[t]);
        cv = fmin(cv, keys[t]);
        keys[t] = hi;
      }
    }
  }
  unsigned short* out = part + ((size_t)(b * NPT + n) * NCH + ch) * KNN;
#pragma unroll
  for (int t = 0; t < KNN; ++t) out[t] = (unsigned short)(__double_as_longlong(keys[t]) & 0xFFF);
}

// ---------------- K1b: merge 16x20 survivors -> exact top-20 ----------------
__global__ __launch_bounds__(256) void k1_merge(const float4* __restrict__ xp,
                                                const unsigned short* __restrict__ part,
                                                int* __restrict__ nbr) {
  int t = blockIdx.x * 256 + threadIdx.x;   // 64 blocks, 16384 threads
  int b = t >> 12, n = t & (NPT - 1);
  const float4* xb = xp + b * NPT;
  float4 q = xb[n];
  float nxx = -q.w;
  const unsigned short* pp = part + (size_t)t * (NCH * KNN);
  double keys[KNN];
#pragma unroll
  for (int k = 0; k < KNN; ++k) keys[k] = -INFINITY;

#pragma unroll 1
  for (int i = 0; i < NCH * KNN; i += 8) {
    int4 pk = *(const int4*)(pp + i);       // 8 u16 indices (16B aligned: 640B stride)
    int j[8];
    j[0] = pk.x & 0xFFFF; j[1] = ((unsigned)pk.x) >> 16;
    j[2] = pk.y & 0xFFFF; j[3] = ((unsigned)pk.y) >> 16;
    j[4] = pk.z & 0xFFFF; j[5] = ((unsigned)pk.z) >> 16;
    j[6] = pk.w & 0xFFFF; j[7] = ((unsigned)pk.w) >> 16;
    float4 c0 = xb[j[0]], c1 = xb[j[1]], c2 = xb[j[2]], c3 = xb[j[3]];
    float4 c4 = xb[j[4]], c5 = xb[j[5]], c6 = xb[j[6]], c7 = xb[j[7]];
    double kk[8];
    kk[0] = pack_key(pd_of(q, nxx, c0), j[0]);
    kk[1] = pack_key(pd_of(q, nxx, c1), j[1]);
    kk[2] = pack_key(pd_of(q, nxx, c2), j[2]);
    kk[3] = pack_key(pd_of(q, nxx, c3), j[3]);
    kk[4] = pack_key(pd_of(q, nxx, c4), j[4]);
    kk[5] = pack_key(pd_of(q, nxx, c5), j[5]);
    kk[6] = pack_key(pd_of(q, nxx, c6), j[6]);
    kk[7] = pack_key(pd_of(q, nxx, c7), j[7]);
#pragma unroll
    for (int u = 0; u < 8; ++u) {
      if (kk[u] > keys[KNN-1]) {
        double cv = kk[u];
#pragma unroll
        for (int s = 0; s < KNN; ++s) {
          double hi = fmax(cv, keys[s]);
          cv = fmin(cv, keys[s]);
          keys[s] = hi;
        }
      }
    }
  }
  int* out = nbr + (size_t)t * KNN;
#pragma unroll
  for (int k = 0; k < KNN; ++k) out[k] = (int)(__double_as_longlong(keys[k]) & 0xFFF);
}

// ---------------- K2: edge-conv 6->64 + BN + ReLU + max over K ----------------
__global__ __launch_bounds__(64) void k2_edge(const float4* __restrict__ xp, const int* __restrict__ nbr,
    const float* __restrict__ w1, const float* __restrict__ g1, const float* __restrict__ b1,
    const float* __restrict__ m1, const float* __restrict__ v1, float* __restrict__ h1) {
  __shared__ float4 sa[C1], se[C1];
  int b = blockIdx.x >> 6;
  int n = ((blockIdx.x & 63) << 6) | threadIdx.x;
  {
    int o = threadIdx.x;
    float inv = g1[o] / sqrtf(v1[o] + BN_EPS);
    float bb = b1[o] - m1[o] * inv;
    const float* w = w1 + o * 6;
    sa[o] = make_float4(w[0]*inv, w[1]*inv, w[2]*inv, 0.f);
    se[o] = make_float4((w[3]-w[0])*inv, (w[4]-w[1])*inv, (w[5]-w[2])*inv, bb);
  }
  __syncthreads();
  const float4* xb = xp + b * NPT;
  float4 q = xb[n];
  float4 nb[KNN];
  const int* nr = nbr + (size_t)(b * NPT + n) * KNN;
#pragma unroll
  for (int k = 0; k < KNN; ++k) nb[k] = xb[nr[k]];
  float* out = h1 + (size_t)(b * NPT + n) * C1;
#pragma unroll 1
  for (int o = 0; o < C1; o += 4) {
    float4 res;
    float* rp = &res.x;
#pragma unroll
    for (int oo = 0; oo < 4; ++oo) {
      float4 a = sa[o+oo], e = se[o+oo];
      float mx = -INFINITY;
#pragma unroll
      for (int k = 0; k < KNN; ++k)
        mx = fmaxf(mx, fmaf(a.z, nb[k].z, fmaf(a.y, nb[k].y, a.x * nb[k].x)));
      float base = fmaf(e.z, q.z, fmaf(e.y, q.y, e.x * q.x)) + e.w;
      rp[oo] = fmaxf(mx + base, 0.f);
    }
    *(float4*)(out + o) = res;
  }
}

// ---------------- K3: conv 64->128 + BN + ReLU ----------------
__global__ __launch_bounds__(64) void k3_conv2(const float* __restrict__ h1,
    const float* __restrict__ w2, const float* __restrict__ g2, const float* __restrict__ b2,
    const float* __restrict__ m2, const float* __restrict__ v2, float* __restrict__ h2) {
  __shared__ float4 sw[C2 * 16];
  __shared__ float sb[C2], sinv[C2];
  int b = blockIdx.x >> 6;
  int n = ((blockIdx.x & 63) << 6) | threadIdx.x;
  for (int o = threadIdx.x; o < C2; o += 64) {
    float inv = g2[o] / sqrtf(v2[o] + BN_EPS);
    sinv[o] = inv;
    sb[o] = b2[o] - m2[o] * inv;
  }
  __syncthreads();
  for (int t = threadIdx.x; t < C2 * 16; t += 64) {
    float4 w = ((const float4*)w2)[t];
    float inv = sinv[t >> 4];
    sw[t] = make_float4(w.x*inv, w.y*inv, w.z*inv, w.w*inv);
  }
  __syncthreads();
  float4 r[16];
  const float4* row = (const float4*)(h1 + (size_t)(b * NPT + n) * C1);
#pragma unroll
  for (int i = 0; i < 16; ++i) r[i] = row[i];
  float* out = h2 + (size_t)(b * NPT + n) * C2;
#pragma unroll 1
  for (int o = 0; o < C2; o += 4) {
    float4 res;
    float* rp = &res.x;
#pragma unroll
    for (int oo = 0; oo < 4; ++oo) {
      const float4* wrow = &sw[(o+oo) * 16];
      float acc = 0.f;
#pragma unroll
      for (int i = 0; i < 16; ++i) {
        float4 w = wrow[i];
        acc = fmaf(r[i].x, w.x, acc);
        acc = fmaf(r[i].y, w.y, acc);
        acc = fmaf(r[i].z, w.z, acc);
        acc = fmaf(r[i].w, w.w, acc);
      }
      rp[oo] = fmaxf(acc + sb[o+oo], 0.f);
    }
    *(float4*)(out + o) = res;
  }
}

// ---------------- K4: conv 128->256 + BN + ReLU fused with global max over N ----------------
__global__ __launch_bounds__(256) void k4_conv3max(const float* __restrict__ h2,
    const float* __restrict__ w3, const float* __restrict__ g3, const float* __restrict__ b3,
    const float* __restrict__ m3, const float* __restrict__ v3, float* __restrict__ feat) {
  __shared__ float4 sw[64 * 32];
  __shared__ float sb[64], sinv[64];
  __shared__ float lw[4 * 64];
  int bid = blockIdx.x;
  int oq = bid & 3, nt = (bid >> 2) & 15, b = bid >> 6;
  int obase = oq * 64;
  if (threadIdx.x < 64) {
    int o = obase + threadIdx.x;
    float inv = g3[o] / sqrtf(v3[o] + BN_EPS);
    sinv[threadIdx.x] = inv;
    sb[threadIdx.x] = b3[o] - m3[o] * inv;
  }
  __syncthreads();
  for (int t = threadIdx.x; t < 64 * 32; t += 256) {
    float4 w = ((const float4*)w3)[obase * 32 + t];
    float inv = sinv[t >> 5];
    sw[t] = make_float4(w.x*inv, w.y*inv, w.z*inv, w.w*inv);
  }
  __syncthreads();
  int n = nt * 256 + threadIdx.x;
  float4 r[32];
  const float4* row = (const float4*)(h2 + (size_t)(b * NPT + n) * C2);
#pragma unroll
  for (int i = 0; i < 32; ++i) r[i] = row[i];
  int lane = threadIdx.x & 63, wid = threadIdx.x >> 6;
#pragma unroll 1
  for (int ol = 0; ol < 64; ++ol) {
    const float4* wrow = &sw[ol * 32];
    float acc = 0.f;
#pragma unroll
    for (int i = 0; i < 32; ++i) {
      float4 w = wrow[i];
      acc = fmaf(r[i].x, w.x, acc);
      acc = fmaf(r[i].y, w.y, acc);
      acc = fmaf(r[i].z, w.z, acc);
      acc = fmaf(r[i].w, w.w, acc);
    }
    float v = fmaxf(acc + sb[ol], 0.f);
#pragma unroll
    for (int m = 32; m; m >>= 1) v = fmaxf(v, __shfl_xor(v, m));
    if (lane == 0) lw[wid * 64 + ol] = v;
  }
  __syncthreads();
  if (threadIdx.x < 64) {
    float m0 = fmaxf(fmaxf(lw[threadIdx.x], lw[64 + threadIdx.x]),
                     fmaxf(lw[128 + threadIdx.x], lw[192 + threadIdx.x]));
    atomicMax((int*)feat + b * C3 + obase + threadIdx.x, __float_as_int(m0));
  }
}

// ---------------- K6: FC head ----------------
__global__ __launch_bounds__(256) void k6_fc(const float* __restrict__ feat,
    const float* __restrict__ fc1w, const float* __restrict__ fc1b,
    const float* __restrict__ fc2w, const float* __restrict__ fc2b, float* __restrict__ out) {
  __shared__ float sf[NB * C3];
  __shared__ float sh[NB * 128];
  for (int t = threadIdx.x; t < NB * C3; t += 256) sf[t] = feat[t];
  __syncthreads();
  for (int t = threadIdx.x; t < NB * 128; t += 256) {
    int b = t >> 7, o = t & 127;
    float acc = fc1b[o];
    const float* w = fc1w + o * C3;
    const float* f = sf + b * C3;
    for (int c = 0; c < C3; ++c) acc = fmaf(f[c], w[c], acc);
    sh[t] = fmaxf(acc, 0.f);
  }
  __syncthreads();
  for (int t = threadIdx.x; t < NB * 40; t += 256) {
    int b = t / 40, o = t % 40;
    float acc = fc2b[o];
    const float* w = fc2w + o * 128;
    const float* hh = sh + b * 128;
    for (int c = 0; c < 128; ++c) acc = fmaf(hh[c], w[c], acc);
    out[b * 40 + o] = acc;
  }
}

extern "C" void kernel_launch(void* const* d_in, const int* in_sizes, int n_in,
                              void* d_out, int out_size, void* d_ws, size_t ws_size,
                              hipStream_t stream) {
  (void)in_sizes; (void)n_in; (void)out_size; (void)ws_size;
  const float* x   = (const float*)d_in[0];
  const float* w1  = (const float*)d_in[1];
  const float* g1  = (const float*)d_in[2];
  const float* b1  = (const float*)d_in[3];
  const float* m1  = (const float*)d_in[4];
  const float* v1  = (const float*)d_in[5];
  const float* w2  = (const float*)d_in[6];
  const float* g2  = (const float*)d_in[7];
  const float* b2  = (const float*)d_in[8];
  const float* m2  = (const float*)d_in[9];
  const float* v2  = (const float*)d_in[10];
  const float* w3  = (const float*)d_in[11];
  const float* g3  = (const float*)d_in[12];
  const float* b3  = (const float*)d_in[13];
  const float* m3  = (const float*)d_in[14];
  const float* v3  = (const float*)d_in[15];
  const float* f1w = (const float*)d_in[16];
  const float* f1b = (const float*)d_in[17];
  const float* f2w = (const float*)d_in[18];
  const float* f2b = (const float*)d_in[19];

  char* ws = (char*)d_ws;
  float4*         xp   = (float4*)ws;                    // [0, 256K)
  float*          feat = (float*)(ws + (1u << 18));      // [256K, +4K)
  int*            nbr  = (int*)(ws + (1u << 19));        // [512K, +1.25M)
  unsigned short* part = (unsigned short*)(ws + (2u << 20)); // [2M, 12M) dead after merge
  float*          h1   = (float*)(ws + (2u << 20));      // [2M, 6M)  overlaps part (after merge)
  float*          h2   = (float*)(ws + (6u << 20));      // [6M, 14M)

  hipMemsetAsync(feat, 0, NB * C3 * sizeof(float), stream);
  k0_pack    <<<64, 256, 0, stream>>>(x, xp);
  k1_part    <<<1024, 256, 0, stream>>>(xp, part);
  k1_merge   <<<64, 256, 0, stream>>>(xp, part, nbr);
  k2_edge    <<<256, 64, 0, stream>>>(xp, nbr, w1, g1, b1, m1, v1, h1);
  k3_conv2   <<<256, 64, 0, stream>>>(h1, w2, g2, b2, m2, v2, h2);
  k4_conv3max<<<256, 256, 0, stream>>>(h2, w3, g3, b3, m3, v3, feat);
  k6_fc      <<<1, 256, 0, stream>>>(feat, f1w, f1b, f2w, f2b, (float*)d_out);
}

// Round 3
// 275.886 us; speedup vs baseline: 2.7296x; 1.1463x over previous
//
#include <hip/hip_runtime.h>
#include <math.h>

#define NB 4
#define NPT 4096
#define KNN 20
#define C1 64
#define C2 128
#define C3 256
#define BN_EPS 1e-5f
#define NCH 8
#define CHSZ 512   // NPT / NCH
#define BATCH 32
#define BSTRIDE 33 // u16 buffer row stride (pad to dodge bank conflicts)

// pd must be computed bit-identically everywhere: pin contraction off.
__device__ __forceinline__ float pd_of(float4 q, float nxx, float4 c) {
#pragma clang fp contract(off)
  float dot = fmaf(q.z, c.z, fmaf(q.y, c.y, q.x * c.x));
  float inner = -2.0f * dot;
  return (nxx - inner) - c.w;
}

// key: f64(pd) with 12-bit candidate index OR'd into the zero low mantissa bits.
// Unique per candidate; max prefers smaller index on pd ties (matches lax.top_k).
__device__ __forceinline__ double pack_key(float pd, int j) {
  return __longlong_as_double(__double_as_longlong((double)pd) | (long long)j);
}

// ---------------- K0: pack {x,y,z,xx} ----------------
__global__ __launch_bounds__(256) void k0_pack(const float* __restrict__ x, float4* __restrict__ xp) {
  int i = blockIdx.x * 256 + threadIdx.x;
  if (i >= NB * NPT) return;
  float a = x[i*3+0], b = x[i*3+1], c = x[i*3+2];
  float xx = fmaf(c, c, fmaf(b, b, a*a));
  xp[i] = make_float4(a, b, c, xx);
}

// ---------------- K1a: per-chunk partial top-20, threshold+buffer+drain ----------------
__global__ __launch_bounds__(256) void k1_part(const float4* __restrict__ xp,
                                               unsigned short* __restrict__ part) {
  __shared__ float4 pts[CHSZ];                       // 8 KiB
  __shared__ unsigned short buf[256 * BSTRIDE];      // ~16.9 KiB
  int blk = blockIdx.x;                 // 512 blocks = 64 qgroups x 8 chunks
  int ch = blk & (NCH - 1);
  int qg = blk >> 3;                    // 0..63
  int b = qg >> 4;                      // 16 qgroups per batch
  int qbase = (qg & 15) << 8;
  const float4* xb = xp + b * NPT;
  int cbase = ch * CHSZ;
  for (int t = threadIdx.x; t < CHSZ; t += 256) pts[t] = xb[cbase + t];
  __syncthreads();

  int n = qbase + threadIdx.x;
  float4 q = xb[n];
  float nxx = -q.w;
  double keys[KNN];
#pragma unroll
  for (int t = 0; t < KNN; ++t) keys[t] = -INFINITY;
  float thr = -INFINITY;                // == pd of keys[19]; exact f32 (lossless filter)
  unsigned short* mybuf = buf + threadIdx.x * BSTRIDE;

#pragma unroll 1
  for (int bs = 0; bs < CHSZ; bs += BATCH) {
    int cnt = 0;
#pragma unroll
    for (int jj = 0; jj < BATCH; ++jj) {
      int j = bs + jj;
      float4 c = pts[j];                // wave-uniform LDS broadcast
      float pd = pd_of(q, nxx, c);
      if (pd >= thr) { mybuf[cnt] = (unsigned short)j; cnt++; }
    }
    // drain: wave iterates max-over-lanes(cnt) times, lanes predicated
#pragma unroll 1
    for (int cc = 0; __any(cc < cnt); ++cc) {
      if (cc < cnt) {
        int j = mybuf[cc];
        float4 c = pts[j];
        float pd = pd_of(q, nxx, c);
        double key = pack_key(pd, cbase + j);
        if (key > keys[KNN-1]) {
          double cv = key;
#pragma unroll
          for (int t = 0; t < KNN; ++t) {
            double hi = fmax(cv, keys[t]);
            cv = fmin(cv, keys[t]);
            keys[t] = hi;
          }
        }
      }
    }
    // threshold = pd part of 20th key (strip index bits; value is f32-exact)
    long long k19 = __double_as_longlong(keys[KNN-1]) & ~0xFFFLL;
    thr = __double2float_rd(__longlong_as_double(k19));
  }
  unsigned short* out = part + ((size_t)(b * NPT + n) * NCH + ch) * KNN;
#pragma unroll
  for (int t = 0; t < KNN; ++t) out[t] = (unsigned short)(__double_as_longlong(keys[t]) & 0xFFF);
}

// ---------------- K1b: merge 8x20 survivors -> exact top-20 ----------------
__global__ __launch_bounds__(64) void k1_merge(const float4* __restrict__ xp,
                                               const unsigned short* __restrict__ part,
                                               int* __restrict__ nbr) {
  int t = blockIdx.x * 64 + threadIdx.x;    // 256 blocks x 64 thr -> 256 CUs
  int b = t >> 12, n = t & (NPT - 1);
  const float4* xb = xp + b * NPT;
  float4 q = xb[n];
  float nxx = -q.w;
  const unsigned short* pp = part + (size_t)t * (NCH * KNN);
  double keys[KNN];
#pragma unroll
  for (int k = 0; k < KNN; ++k) keys[k] = -INFINITY;

#pragma unroll 1
  for (int i = 0; i < NCH * KNN; i += 8) {
    int4 pk = *(const int4*)(pp + i);       // 8 u16 indices (320B row stride, 16B aligned)
    int j[8];
    j[0] = pk.x & 0xFFFF; j[1] = ((unsigned)pk.x) >> 16;
    j[2] = pk.y & 0xFFFF; j[3] = ((unsigned)pk.y) >> 16;
    j[4] = pk.z & 0xFFFF; j[5] = ((unsigned)pk.z) >> 16;
    j[6] = pk.w & 0xFFFF; j[7] = ((unsigned)pk.w) >> 16;
    float4 c0 = xb[j[0]], c1 = xb[j[1]], c2 = xb[j[2]], c3 = xb[j[3]];
    float4 c4 = xb[j[4]], c5 = xb[j[5]], c6 = xb[j[6]], c7 = xb[j[7]];
    double kk[8];
    kk[0] = pack_key(pd_of(q, nxx, c0), j[0]);
    kk[1] = pack_key(pd_of(q, nxx, c1), j[1]);
    kk[2] = pack_key(pd_of(q, nxx, c2), j[2]);
    kk[3] = pack_key(pd_of(q, nxx, c3), j[3]);
    kk[4] = pack_key(pd_of(q, nxx, c4), j[4]);
    kk[5] = pack_key(pd_of(q, nxx, c5), j[5]);
    kk[6] = pack_key(pd_of(q, nxx, c6), j[6]);
    kk[7] = pack_key(pd_of(q, nxx, c7), j[7]);
#pragma unroll
    for (int u = 0; u < 8; ++u) {
      if (kk[u] > keys[KNN-1]) {
        double cv = kk[u];
#pragma unroll
        for (int s = 0; s < KNN; ++s) {
          double hi = fmax(cv, keys[s]);
          cv = fmin(cv, keys[s]);
          keys[s] = hi;
        }
      }
    }
  }
  int* out = nbr + (size_t)t * KNN;
#pragma unroll
  for (int k = 0; k < KNN; ++k) out[k] = (int)(__double_as_longlong(keys[k]) & 0xFFF);
}

// ---------------- K2: edge-conv 6->64 + BN + ReLU + max over K (out-split x2) ----------------
__global__ __launch_bounds__(128) void k2_edge(const float4* __restrict__ xp, const int* __restrict__ nbr,
    const float* __restrict__ w1, const float* __restrict__ g1, const float* __restrict__ b1,
    const float* __restrict__ m1, const float* __restrict__ v1, float* __restrict__ h1) {
  __shared__ float4 sa[C1], se[C1];
  int tid = threadIdx.x;
  if (tid < C1) {
    int o = tid;
    float inv = g1[o] / sqrtf(v1[o] + BN_EPS);
    float bb = b1[o] - m1[o] * inv;
    const float* w = w1 + o * 6;
    sa[o] = make_float4(w[0]*inv, w[1]*inv, w[2]*inv, 0.f);
    se[o] = make_float4((w[3]-w[0])*inv, (w[4]-w[1])*inv, (w[5]-w[2])*inv, bb);
  }
  __syncthreads();
  int gp = blockIdx.x * 64 + (tid & 63);    // 256 blocks
  int h = tid >> 6;                         // out half
  int b = gp >> 12, n = gp & (NPT - 1);
  const float4* xb = xp + b * NPT;
  float4 q = xb[n];
  float4 nb[KNN];
  const int* nr = nbr + (size_t)gp * KNN;
#pragma unroll
  for (int k = 0; k < KNN; ++k) nb[k] = xb[nr[k]];
  float* out = h1 + (size_t)gp * C1;
  int obase = h * 32;
#pragma unroll 1
  for (int o = obase; o < obase + 32; o += 4) {
    float4 res;
    float* rp = &res.x;
#pragma unroll
    for (int oo = 0; oo < 4; ++oo) {
      float4 a = sa[o+oo], e = se[o+oo];
      float mx = -INFINITY;
#pragma unroll
      for (int k = 0; k < KNN; ++k)
        mx = fmaxf(mx, fmaf(a.z, nb[k].z, fmaf(a.y, nb[k].y, a.x * nb[k].x)));
      float base = fmaf(e.z, q.z, fmaf(e.y, q.y, e.x * q.x)) + e.w;
      rp[oo] = fmaxf(mx + base, 0.f);
    }
    *(float4*)(out + o) = res;
  }
}

// ---------------- K3: conv 64->128 + BN + ReLU (out-quarter split) ----------------
__global__ __launch_bounds__(256) void k3_conv2(const float* __restrict__ h1,
    const float* __restrict__ w2, const float* __restrict__ g2, const float* __restrict__ b2,
    const float* __restrict__ m2, const float* __restrict__ v2, float* __restrict__ h2) {
  __shared__ float4 sw[32 * 16];            // 8 KiB: this block's 32 outs
  __shared__ float sb[32];
  int qd = blockIdx.x & 3, ng = blockIdx.x >> 2;   // 256 blocks
  int obase = qd * 32;
  if (threadIdx.x < 32) {
    int o = obase + threadIdx.x;
    float inv = g2[o] / sqrtf(v2[o] + BN_EPS);
    sb[threadIdx.x] = b2[o] - m2[o] * inv;
  }
  for (int t = threadIdx.x; t < 32 * 16; t += 256) {
    int o = obase + (t >> 4);
    float inv = g2[o] / sqrtf(v2[o] + BN_EPS);
    float4 w = ((const float4*)w2)[o * 16 + (t & 15)];
    sw[t] = make_float4(w.x*inv, w.y*inv, w.z*inv, w.w*inv);
  }
  __syncthreads();
  int gp = ng * 256 + threadIdx.x;
  float4 r[16];
  const float4* row = (const float4*)(h1 + (size_t)gp * C1);
#pragma unroll
  for (int i = 0; i < 16; ++i) r[i] = row[i];
  float* out = h2 + (size_t)gp * C2 + obase;
#pragma unroll 1
  for (int o = 0; o < 32; o += 4) {
    float4 res;
    float* rp = &res.x;
#pragma unroll
    for (int oo = 0; oo < 4; ++oo) {
      const float4* wrow = &sw[(o+oo) * 16];
      float acc = 0.f;
#pragma unroll
      for (int i = 0; i < 16; ++i) {
        float4 w = wrow[i];
        acc = fmaf(r[i].x, w.x, acc);
        acc = fmaf(r[i].y, w.y, acc);
        acc = fmaf(r[i].z, w.z, acc);
        acc = fmaf(r[i].w, w.w, acc);
      }
      rp[oo] = fmaxf(acc + sb[o+oo], 0.f);
    }
    *(float4*)(out + o) = res;
  }
}

// ---------------- K4: conv 128->256 + BN + ReLU fused with global max over N ----------------
__global__ __launch_bounds__(256) void k4_conv3max(const float* __restrict__ h2,
    const float* __restrict__ w3, const float* __restrict__ g3, const float* __restrict__ b3,
    const float* __restrict__ m3, const float* __restrict__ v3, float* __restrict__ feat) {
  __shared__ float4 sw[64 * 32];
  __shared__ float sb[64], sinv[64];
  __shared__ float lw[4 * 64];
  int bid = blockIdx.x;
  int oq = bid & 3, nt = (bid >> 2) & 15, b = bid >> 6;
  int obase = oq * 64;
  if (threadIdx.x < 64) {
    int o = obase + threadIdx.x;
    float inv = g3[o] / sqrtf(v3[o] + BN_EPS);
    sinv[threadIdx.x] = inv;
    sb[threadIdx.x] = b3[o] - m3[o] * inv;
  }
  __syncthreads();
  for (int t = threadIdx.x; t < 64 * 32; t += 256) {
    float4 w = ((const float4*)w3)[obase * 32 + t];
    float inv = sinv[t >> 5];
    sw[t] = make_float4(w.x*inv, w.y*inv, w.z*inv, w.w*inv);
  }
  __syncthreads();
  int n = nt * 256 + threadIdx.x;
  float4 r[32];
  const float4* row = (const float4*)(h2 + (size_t)(b * NPT + n) * C2);
#pragma unroll
  for (int i = 0; i < 32; ++i) r[i] = row[i];
  int lane = threadIdx.x & 63, wid = threadIdx.x >> 6;
#pragma unroll 1
  for (int ol = 0; ol < 64; ++ol) {
    const float4* wrow = &sw[ol * 32];
    float acc = 0.f;
#pragma unroll
    for (int i = 0; i < 32; ++i) {
      float4 w = wrow[i];
      acc = fmaf(r[i].x, w.x, acc);
      acc = fmaf(r[i].y, w.y, acc);
      acc = fmaf(r[i].z, w.z, acc);
      acc = fmaf(r[i].w, w.w, acc);
    }
    float v = fmaxf(acc + sb[ol], 0.f);
#pragma unroll
    for (int m = 32; m; m >>= 1) v = fmaxf(v, __shfl_xor(v, m));
    if (lane == 0) lw[wid * 64 + ol] = v;
  }
  __syncthreads();
  if (threadIdx.x < 64) {
    float m0 = fmaxf(fmaxf(lw[threadIdx.x], lw[64 + threadIdx.x]),
                     fmaxf(lw[128 + threadIdx.x], lw[192 + threadIdx.x]));
    atomicMax((int*)feat + b * C3 + obase + threadIdx.x, __float_as_int(m0));
  }
}

// ---------------- K6: FC head ----------------
__global__ __launch_bounds__(256) void k6_fc(const float* __restrict__ feat,
    const float* __restrict__ fc1w, const float* __restrict__ fc1b,
    const float* __restrict__ fc2w, const float* __restrict__ fc2b, float* __restrict__ out) {
  __shared__ float sf[NB * C3];
  __shared__ float sh[NB * 128];
  for (int t = threadIdx.x; t < NB * C3; t += 256) sf[t] = feat[t];
  __syncthreads();
  for (int t = threadIdx.x; t < NB * 128; t += 256) {
    int b = t >> 7, o = t & 127;
    float acc = fc1b[o];
    const float* w = fc1w + o * C3;
    const float* f = sf + b * C3;
    for (int c = 0; c < C3; ++c) acc = fmaf(f[c], w[c], acc);
    sh[t] = fmaxf(acc, 0.f);
  }
  __syncthreads();
  for (int t = threadIdx.x; t < NB * 40; t += 256) {
    int b = t / 40, o = t % 40;
    float acc = fc2b[o];
    const float* w = fc2w + o * 128;
    const float* hh = sh + b * 128;
    for (int c = 0; c < 128; ++c) acc = fmaf(hh[c], w[c], acc);
    out[b * 40 + o] = acc;
  }
}

extern "C" void kernel_launch(void* const* d_in, const int* in_sizes, int n_in,
                              void* d_out, int out_size, void* d_ws, size_t ws_size,
                              hipStream_t stream) {
  (void)in_sizes; (void)n_in; (void)out_size; (void)ws_size;
  const float* x   = (const float*)d_in[0];
  const float* w1  = (const float*)d_in[1];
  const float* g1  = (const float*)d_in[2];
  const float* b1  = (const float*)d_in[3];
  const float* m1  = (const float*)d_in[4];
  const float* v1  = (const float*)d_in[5];
  const float* w2  = (const float*)d_in[6];
  const float* g2  = (const float*)d_in[7];
  const float* b2  = (const float*)d_in[8];
  const float* m2  = (const float*)d_in[9];
  const float* v2  = (const float*)d_in[10];
  const float* w3  = (const float*)d_in[11];
  const float* g3  = (const float*)d_in[12];
  const float* b3  = (const float*)d_in[13];
  const float* m3  = (const float*)d_in[14];
  const float* v3  = (const float*)d_in[15];
  const float* f1w = (const float*)d_in[16];
  const float* f1b = (const float*)d_in[17];
  const float* f2w = (const float*)d_in[18];
  const float* f2b = (const float*)d_in[19];

  char* ws = (char*)d_ws;
  float4*         xp   = (float4*)ws;                    // [0, 256K)
  float*          feat = (float*)(ws + (1u << 18));      // [256K, +4K)
  int*            nbr  = (int*)(ws + (1u << 19));        // [512K, +1.25M)
  unsigned short* part = (unsigned short*)(ws + (2u << 20)); // [2M, +5M) dead after merge
  float*          h1   = (float*)(ws + (2u << 20));      // [2M, 6M)  overlaps part (after merge)
  float*          h2   = (float*)(ws + (6u << 20));      // [6M, 14M) written after merge

  hipMemsetAsync(feat, 0, NB * C3 * sizeof(float), stream);
  k0_pack    <<<64, 256, 0, stream>>>(x, xp);
  k1_part    <<<512, 256, 0, stream>>>(xp, part);
  k1_merge   <<<256, 64, 0, stream>>>(xp, part, nbr);
  k2_edge    <<<256, 128, 0, stream>>>(xp, nbr, w1, g1, b1, m1, v1, h1);
  k3_conv2   <<<256, 256, 0, stream>>>(h1, w2, g2, b2, m2, v2, h2);
  k4_conv3max<<<256, 256, 0, stream>>>(h2, w3, g3, b3, m3, v3, feat);
  k6_fc      <<<1, 256, 0, stream>>>(feat, f1w, f1b, f2w, f2b, (float*)d_out);
}